// Round 10
// baseline (301.003 us; speedup 1.0000x reference)
//
#include <hip/hip_runtime.h>
#include <stdint.h>

// Problem constants
#define BB   16
#define TT   4096
#define DIN  64
#define DOUT 64
#define HH   128
#define LCH  64
#define WARM 32
#define SS   96
#define TAPS 32

// HARD-WON FACTS (rounds 0-9):
//  * d_out = 4,194,304 float32 (16 MB): REAL PART only, flat (b*4096+t)*64+o.
//  * 32-tap truncation numerically free (absmax 0.0625 == exact path).
//  * R9: conv-GEMM works (72us); 11 precompute launches cost ~204us of
//    launch overhead; k_conv had 1 wave/SIMD (no latency hiding).
//  * This round: ONE mega-kernel (grid barrier via d_ws atomic counter;
//    LDS=80KB forces 1 block/CU so 256 blocks co-resident => barrier safe)
//    + conv at 512 threads (2 waves/SIMD).  ws layout unchanged (3 MB).

typedef __attribute__((ext_vector_type(8))) short short8;
typedef __attribute__((ext_vector_type(4))) float f32x4;

// ---------- bf16 pack helpers (RNE) ----------
__device__ __forceinline__ uint32_t f2bf(float f) {
  uint32_t x = __float_as_uint(f);
  return (x + 0x7FFFu + ((x >> 16) & 1u)) >> 16;
}
__device__ __forceinline__ uint32_t pack_bf(float re, float im) {
  return f2bf(re) | (f2bf(im) << 16);
}
__device__ __forceinline__ float bf_re(uint32_t u) { return __uint_as_float(u << 16); }
__device__ __forceinline__ float bf_im(uint32_t u) { return __uint_as_float(u & 0xFFFF0000u); }

// fragment-major index for W (B-operand of mfma_f32_16x16x32_bf16) [R9-verified]
__device__ __forceinline__ int fragIdx(int d, int o, int part, int kk) {
  const int ks = part * 2 + (kk >> 5);
  const int k32 = kk & 31;
  const int nt = o >> 4;
  const int lane = ((k32 >> 3) << 4) | (o & 15);
  return (((d * 16 + ks * 4 + nt) * 64) + lane) * 8 + (k32 & 7);
}

// ---------- grid barrier (all 256 blocks co-resident: LDS forces 1 blk/CU) ----
__device__ __forceinline__ void gbar(uint32_t* cnt, uint32_t target) {
  __syncthreads();
  if (threadIdx.x == 0) {
    __threadfence();                       // release prior global writes
    atomicAdd(cnt, 1u);
    int g = 0;
    while (atomicAdd(cnt, 0u) < target) {  // coherent atomic read
      __builtin_amdgcn_s_sleep(2);
      if (++g > 8000000) break;            // bailout: wrong > hung
    }
    __threadfence();
  }
  __syncthreads();
}

// ---------- phase helpers (512-thread blocks; compute on tid<256) ----------
__device__ __forceinline__ void sq_tile(
    const float* ar, const float* ai, int fromPlanes,
    const float2* src, float2* dst, int blk, unsigned char* smem) {
  float2* band  = (float2*)smem;              // 16x128
  float2* panel = (float2*)(smem + 16384);    // 32x128
  const int tid = threadIdx.x;
  const int ib = blk >> 3, jb = blk & 7;
  for (int idx = tid; idx < 2048; idx += 512) {
    const int e = (ib * 16 + (idx >> 7)) * HH + (idx & 127);
    band[idx] = fromPlanes ? make_float2(ar[e], ai[e]) : src[e];
  }
  const int jt = tid & 15, it = (tid >> 4) & 15;
  float sre = 0.f, sim = 0.f;
  for (int kp = 0; kp < 4; ++kp) {
    __syncthreads();
    for (int idx = tid; idx < 4096; idx += 512) {
      const int e = (kp * 32 + (idx >> 7)) * HH + (idx & 127);
      panel[idx] = fromPlanes ? make_float2(ar[e], ai[e]) : src[e];
    }
    __syncthreads();
    if (tid < 256) {
#pragma unroll 4
      for (int kk = 0; kk < 32; ++kk) {
        const float2 a = band[it * HH + kp * 32 + kk];
        const float2 bv = panel[kk * HH + jb * 16 + jt];
        sre = fmaf(a.x, bv.x, sre); sre = fmaf(-a.y, bv.y, sre);
        sim = fmaf(a.x, bv.y, sim); sim = fmaf(a.y, bv.x, sim);
      }
    }
  }
  if (tid < 256) dst[(ib * 16 + it) * HH + jb * 16 + jt] = make_float2(sre, sim);
}

__device__ __forceinline__ void pmul_tile(
    const float* ar, const float* ai, int aPlanes, const float2* Aflat,
    const float* sr, const float* si, int sPlanes, const float2* srcP,
    float2* dst, int tile, unsigned char* smem) {
  float2* Pl = (float2*)smem;   // 8192 f2 = 64 KB
  const int tid = threadIdx.x;
  if (sPlanes) {
    for (int idx = tid; idx < 8192; idx += 512)
      Pl[idx] = make_float2(sr[idx], si[idx]);
  } else {
    const float4* s4 = (const float4*)srcP;
    float4* d4 = (float4*)Pl;
    for (int idx = tid; idx < 4096; idx += 512) d4[idx] = s4[idx];
  }
  __syncthreads();
  if (tid < 256) {
    const int i = tile * 16 + (tid >> 4);
    const int c0 = (tid & 15) * 4;
    float accr[4] = {0.f,0.f,0.f,0.f}, acim[4] = {0.f,0.f,0.f,0.f};
#pragma unroll 4
    for (int k = 0; k < 128; ++k) {
      const float2 a = aPlanes ? make_float2(ar[i * 128 + k], ai[i * 128 + k])
                               : Aflat[i * 128 + k];
      const float4 p01 = *(const float4*)&Pl[k * 64 + c0];
      const float4 p23 = *(const float4*)&Pl[k * 64 + c0 + 2];
      accr[0] = fmaf(a.x, p01.x, fmaf(-a.y, p01.y, accr[0]));
      acim[0] = fmaf(a.x, p01.y, fmaf( a.y, p01.x, acim[0]));
      accr[1] = fmaf(a.x, p01.z, fmaf(-a.y, p01.w, accr[1]));
      acim[1] = fmaf(a.x, p01.w, fmaf( a.y, p01.z, acim[1]));
      accr[2] = fmaf(a.x, p23.x, fmaf(-a.y, p23.y, accr[2]));
      acim[2] = fmaf(a.x, p23.y, fmaf( a.y, p23.x, acim[2]));
      accr[3] = fmaf(a.x, p23.z, fmaf(-a.y, p23.w, accr[3]));
      acim[3] = fmaf(a.x, p23.w, fmaf( a.y, p23.z, acim[3]));
    }
#pragma unroll
    for (int cc = 0; cc < 4; ++cc)
      dst[i * 64 + c0 + cc] = make_float2(accr[cc], acim[cc]);
  }
}

__device__ __forceinline__ void makeV_tile(
    int d, int tile, const float2* P,
    const float* wir_, const float* wii_,
    const float* wor, const float* woi, short* Wf, unsigned char* smem) {
  float2* Pl = (float2*)smem;
  const int tid = threadIdx.x;
  if (d == 0) {
    for (int idx = tid; idx < 8192; idx += 512)
      Pl[idx] = make_float2(wir_[idx], wii_[idx]);
  } else {
    const float4* s4 = (const float4*)(P + (size_t)d * 8192);
    float4* d4 = (float4*)Pl;
    for (int idx = tid; idx < 4096; idx += 512) d4[idx] = s4[idx];
  }
  __syncthreads();
  if (tid < 256) {
    const int o = tile * 16 + (tid >> 4);
    const int c0 = (tid & 15) * 4;
    float accr[4] = {0.f,0.f,0.f,0.f}, acim[4] = {0.f,0.f,0.f,0.f};
#pragma unroll 4
    for (int k = 0; k < 128; ++k) {
      const float2 a = make_float2(wor[o * 128 + k], woi[o * 128 + k]);
      const float4 p01 = *(const float4*)&Pl[k * 64 + c0];
      const float4 p23 = *(const float4*)&Pl[k * 64 + c0 + 2];
      accr[0] = fmaf(a.x, p01.x, fmaf(-a.y, p01.y, accr[0]));
      acim[0] = fmaf(a.x, p01.y, fmaf( a.y, p01.x, acim[0]));
      accr[1] = fmaf(a.x, p01.z, fmaf(-a.y, p01.w, accr[1]));
      acim[1] = fmaf(a.x, p01.w, fmaf( a.y, p01.z, acim[1]));
      accr[2] = fmaf(a.x, p23.x, fmaf(-a.y, p23.y, accr[2]));
      acim[2] = fmaf(a.x, p23.y, fmaf( a.y, p23.x, acim[2]));
      accr[3] = fmaf(a.x, p23.z, fmaf(-a.y, p23.w, accr[3]));
      acim[3] = fmaf(a.x, p23.w, fmaf( a.y, p23.z, acim[3]));
    }
#pragma unroll
    for (int cc = 0; cc < 4; ++cc) {
      const float re = accr[cc], im = acim[cc];
      float tr, ti;
      switch (d & 3) {
        case 0: tr = re;  ti = im;  break;
        case 1: tr = -im; ti = re;  break;
        case 2: tr = -re; ti = -im; break;
        default: tr = im; ti = -re; break;
      }
      const int kk = c0 + cc;
      Wf[fragIdx(d, o, 0, kk)] = (short)f2bf(tr);
      Wf[fragIdx(d, o, 1, kk)] = (short)f2bf(-ti);
    }
  }
}

// conv phase: 512 threads = 8 waves, each wave 32 rows (2 m-tiles x 4 n-tiles)
__device__ __forceinline__ void conv_part(
    const float* xr, const float* xi, const short* Wf, float* out,
    int blk, unsigned char* smem) {
  short* xs = (short*)smem;   // 288*136 shorts = 78336 B
  const int tid = threadIdx.x;
  const int b = blk & 15;
  const int t0 = (blk >> 4) * 256;
  for (int idx = tid; idx < 288 * 16; idx += 512) {
    const int r = idx >> 4;
    const int kq = (idx & 15) << 2;
    const int t = t0 + r - 32;
    uint32_t r01 = 0u, r23 = 0u, i01 = 0u, i23 = 0u;
    if (t >= 0) {
      const size_t g = ((size_t)b * TT + t) * 64 + kq;
      const float4 vr = *(const float4*)(xr + g);
      const float4 vi = *(const float4*)(xi + g);
      r01 = f2bf(vr.x) | (f2bf(vr.y) << 16);
      r23 = f2bf(vr.z) | (f2bf(vr.w) << 16);
      i01 = f2bf(vi.x) | (f2bf(vi.y) << 16);
      i23 = f2bf(vi.z) | (f2bf(vi.w) << 16);
    }
    *(uint2*)&xs[r * 136 + kq]      = make_uint2(r01, r23);
    *(uint2*)&xs[r * 136 + 64 + kq] = make_uint2(i01, i23);
  }
  __syncthreads();

  const int w = tid >> 6;        // 0..7
  const int lane = tid & 63;
  const int lm = lane & 15;
  const int kc8 = (lane >> 4) << 3;
  f32x4 acc[2][4];
#pragma unroll
  for (int mi = 0; mi < 2; ++mi)
#pragma unroll
    for (int nt = 0; nt < 4; ++nt) acc[mi][nt] = (f32x4){0.f, 0.f, 0.f, 0.f};

#pragma unroll 2
  for (int d = 0; d < TAPS; ++d) {
    const int rb = 32 - d + w * 32 + lm;
#pragma unroll
    for (int ks = 0; ks < 4; ++ks) {
      const int col = (ks >> 1) * 64 + (ks & 1) * 32 + kc8;
      short8 bq[4];
#pragma unroll
      for (int nt = 0; nt < 4; ++nt)
        bq[nt] = *(const short8*)(Wf + (((d * 16 + ks * 4 + nt) * 64 + lane) << 3));
      short8 aq[2];
#pragma unroll
      for (int mi = 0; mi < 2; ++mi)
        aq[mi] = *(const short8*)&xs[(rb + mi * 16) * 136 + col];
#pragma unroll
      for (int mi = 0; mi < 2; ++mi)
#pragma unroll
        for (int nt = 0; nt < 4; ++nt)
          acc[mi][nt] = __builtin_amdgcn_mfma_f32_16x16x32_bf16(
              aq[mi], bq[nt], acc[mi][nt], 0, 0, 0);
    }
  }
  const int mrow = w * 32 + ((lane >> 4) << 2);
#pragma unroll
  for (int mi = 0; mi < 2; ++mi) {
#pragma unroll
    for (int nt = 0; nt < 4; ++nt) {
      const int o = nt * 16 + lm;
      float* p = out + ((size_t)b * TT + t0 + mrow + mi * 16) * 64 + o;
#pragma unroll
      for (int rg = 0; rg < 4; ++rg) p[(size_t)rg * 64] = acc[mi][nt][rg];
    }
  }
}

// ---------------------------------------------------------------------------
// THE MEGA-KERNEL: 256 blocks x 512 threads.  LDS padded to 81920 B so only
// 1 block/CU fits => all 256 blocks co-resident => grid barrier is safe.
// ---------------------------------------------------------------------------
__global__ __launch_bounds__(512, 2) void k_mega(
    const float* __restrict__ xr, const float* __restrict__ xi,
    const float* __restrict__ wir, const float* __restrict__ wii,
    const float* __restrict__ whr, const float* __restrict__ whi,
    const float* __restrict__ wor, const float* __restrict__ woi,
    float* __restrict__ out,
    float2* Wp0, float2* Wp1, float2* Wp2, float2* Wp3,
    float2* P, short* Wf, uint32_t* cnt) {
  __shared__ __align__(16) unsigned char smem[81920];
  const int blk = blockIdx.x;

  // ph1: Wh2 | P1 = Wh*Wi | V0
  if (blk < 64)       sq_tile(whr, whi, 1, Wp0, Wp0, blk, smem);
  else if (blk < 72)  pmul_tile(whr, whi, 1, Wp0, wir, wii, 1, P,
                                P + 8192, blk - 64, smem);
  else if (blk < 76)  makeV_tile(0, blk - 72, P, wir, wii, wor, woi, Wf, smem);
  gbar(cnt, 256);

  // ph2: Wh4 | P2,P3 | V1
  if (blk < 64)       sq_tile(whr, whi, 0, Wp0, Wp1, blk, smem);
  else if (blk < 80) {
    const int j = (blk - 64) >> 3, tile = (blk - 64) & 7;
    pmul_tile(whr, whi, 0, Wp0, wir, wii, j == 0, P + (size_t)j * 8192,
              P + (size_t)(2 + j) * 8192, tile, smem);
  } else if (blk < 84) makeV_tile(1, blk - 80, P, wir, wii, wor, woi, Wf, smem);
  gbar(cnt, 512);

  // ph3: Wh8 | P4..7 | V2,V3
  if (blk < 64)       sq_tile(whr, whi, 0, Wp1, Wp2, blk, smem);
  else if (blk < 96) {
    const int j = (blk - 64) >> 3, tile = (blk - 64) & 7;
    pmul_tile(whr, whi, 0, Wp1, wir, wii, j == 0, P + (size_t)j * 8192,
              P + (size_t)(4 + j) * 8192, tile, smem);
  } else if (blk < 104)
    makeV_tile(2 + ((blk - 96) >> 2), (blk - 96) & 3, P, wir, wii, wor, woi, Wf, smem);
  gbar(cnt, 768);

  // ph4: Wh16 | P8..15 | V4..7
  if (blk < 64)       sq_tile(whr, whi, 0, Wp2, Wp3, blk, smem);
  else if (blk < 128) {
    const int j = (blk - 64) >> 3, tile = (blk - 64) & 7;
    pmul_tile(whr, whi, 0, Wp2, wir, wii, j == 0, P + (size_t)j * 8192,
              P + (size_t)(8 + j) * 8192, tile, smem);
  } else if (blk < 144)
    makeV_tile(4 + ((blk - 128) >> 2), (blk - 128) & 3, P, wir, wii, wor, woi, Wf, smem);
  gbar(cnt, 1024);

  // ph5: P16..31 | V8..15
  if (blk < 128) {
    const int j = blk >> 3, tile = blk & 7;
    pmul_tile(whr, whi, 0, Wp3, wir, wii, j == 0, P + (size_t)j * 8192,
              P + (size_t)(16 + j) * 8192, tile, smem);
  } else if (blk < 160)
    makeV_tile(8 + ((blk - 128) >> 2), (blk - 128) & 3, P, wir, wii, wor, woi, Wf, smem);
  gbar(cnt, 1280);

  // ph6: V16..31
  if (blk < 64)
    makeV_tile(16 + (blk >> 2), blk & 3, P, wir, wii, wor, woi, Wf, smem);
  gbar(cnt, 1536);

  // ph7: the conv GEMM (all 256 blocks)
  conv_part(xr, xi, Wf, out, blk, smem);
}

// ---------------------------------------------------------------------------
// FALLBACK (R8, proven 596 us): single fused truncated-scan kernel.
// ---------------------------------------------------------------------------
__global__ __launch_bounds__(256) void k_fused(
    const float* __restrict__ xr, const float* __restrict__ xi,
    const float* __restrict__ wir, const float* __restrict__ wii,
    const float* __restrict__ whr, const float* __restrict__ whi,
    const float* __restrict__ wor, const float* __restrict__ woi,
    float* __restrict__ out) {
  __shared__ __align__(16) unsigned char smem[63488];
  uint32_t* xpl  = (uint32_t*)smem;
  uint32_t* wiq  = (uint32_t*)(smem + 49152);
  uint32_t* xtq  = (uint32_t*)(smem + 57344);
  float2*   part = (float2*)(smem + 49152);
  float2*   hbuf = (float2*)(smem + 59392);
  uint32_t* woA  = (uint32_t*)smem;
  const int tid = threadIdx.x;
  const int c = blockIdx.x >> 4;
  const int b = blockIdx.x & 15;
  const int t0 = c * LCH - WARM;

  const int ho = tid & 31;
  const int tg = tid >> 5;
  float accr[4][12], acci[4][12];
#pragma unroll
  for (int a = 0; a < 4; ++a)
#pragma unroll
    for (int t = 0; t < 12; ++t) { accr[a][t] = 0.f; acci[a][t] = 0.f; }

#pragma unroll 1
  for (int q = 0; q < 4; ++q) {
    if (q) __syncthreads();
    for (int idx = tid; idx < 16 * HH; idx += 256) {
      const int dd = idx & 15, h = idx >> 4;
      const int g = h * DIN + q * 16 + dd;
      wiq[dd * 128 + h] = pack_bf(wir[g], wii[g]);
    }
    for (int idx = tid; idx < 16 * SS; idx += 256) {
      const int dd = idx & 15, s = idx >> 4;
      const int t = t0 + s;
      uint32_t v = 0u;
      if (t >= 0) {
        const size_t g = ((size_t)b * TT + t) * DIN + q * 16 + dd;
        v = pack_bf(xr[g], xi[g]);
      }
      xtq[dd * 96 + s] = v;
    }
    __syncthreads();
#pragma unroll 4
    for (int dd = 0; dd < 16; ++dd) {
      const uint4 wv  = *(const uint4*)&wiq[dd * 128 + ho * 4];
      const uint4 xv0 = *(const uint4*)&xtq[dd * 96 + tg * 12];
      const uint4 xv1 = *(const uint4*)&xtq[dd * 96 + tg * 12 + 4];
      const uint4 xv2 = *(const uint4*)&xtq[dd * 96 + tg * 12 + 8];
      float wre[4], wim[4], xre[12], xim[12];
      wre[0] = bf_re(wv.x); wim[0] = bf_im(wv.x);
      wre[1] = bf_re(wv.y); wim[1] = bf_im(wv.y);
      wre[2] = bf_re(wv.z); wim[2] = bf_im(wv.z);
      wre[3] = bf_re(wv.w); wim[3] = bf_im(wv.w);
      xre[0] = bf_re(xv0.x); xim[0] = bf_im(xv0.x);
      xre[1] = bf_re(xv0.y); xim[1] = bf_im(xv0.y);
      xre[2] = bf_re(xv0.z); xim[2] = bf_im(xv0.z);
      xre[3] = bf_re(xv0.w); xim[3] = bf_im(xv0.w);
      xre[4] = bf_re(xv1.x); xim[4] = bf_im(xv1.x);
      xre[5] = bf_re(xv1.y); xim[5] = bf_im(xv1.y);
      xre[6] = bf_re(xv1.z); xim[6] = bf_im(xv1.z);
      xre[7] = bf_re(xv1.w); xim[7] = bf_im(xv1.w);
      xre[8] = bf_re(xv2.x); xim[8] = bf_im(xv2.x);
      xre[9] = bf_re(xv2.y); xim[9] = bf_im(xv2.y);
      xre[10] = bf_re(xv2.z); xim[10] = bf_im(xv2.z);
      xre[11] = bf_re(xv2.w); xim[11] = bf_im(xv2.w);
#pragma unroll
      for (int a = 0; a < 4; ++a)
#pragma unroll
        for (int t = 0; t < 12; ++t) {
          accr[a][t] = fmaf(wre[a], xre[t], accr[a][t]);
          accr[a][t] = fmaf(-wim[a], xim[t], accr[a][t]);
          acci[a][t] = fmaf(wre[a], xim[t], acci[a][t]);
          acci[a][t] = fmaf(wim[a], xre[t], acci[a][t]);
        }
    }
  }
  __syncthreads();

#pragma unroll
  for (int tt = 0; tt < 12; ++tt) {
    uint4 v;
    v.x = pack_bf(accr[0][tt], acci[0][tt]);
    v.y = pack_bf(accr[1][tt], acci[1][tt]);
    v.z = pack_bf(accr[2][tt], acci[2][tt]);
    v.w = pack_bf(accr[3][tt], acci[3][tt]);
    *(uint4*)&xpl[(tg * 12 + tt) * 128 + ho * 4] = v;
  }
  if (tid < HH) hbuf[tid] = make_float2(0.f, 0.f);

  const int p8 = tid & 7;
  const int jg = tid >> 3;
  float wr[4][16], wim_[4][16];
#pragma unroll
  for (int a = 0; a < 4; ++a)
#pragma unroll
    for (int i = 0; i < 16; i += 4) {
      const float4 vr = *(const float4*)(whr + (size_t)(jg * 4 + a) * HH + p8 * 16 + i);
      wr[a][i] = vr.x; wr[a][i + 1] = vr.y; wr[a][i + 2] = vr.z; wr[a][i + 3] = vr.w;
      const float4 vi = *(const float4*)(whi + (size_t)(jg * 4 + a) * HH + p8 * 16 + i);
      wim_[a][i] = vi.x; wim_[a][i + 1] = vi.y; wim_[a][i + 2] = vi.z; wim_[a][i + 3] = vi.w;
    }
  __syncthreads();

#pragma unroll 1
  for (int s = 0; s < SS; ++s) {
    const uint32_t u = (tid < HH) ? xpl[s * 128 + tid] : 0u;
    float sre[4] = {0.f, 0.f, 0.f, 0.f}, sim[4] = {0.f, 0.f, 0.f, 0.f};
#pragma unroll
    for (int i = 0; i < 16; ++i) {
      const float2 hv = hbuf[i * 8 + p8];
#pragma unroll
      for (int a = 0; a < 4; ++a) {
        sre[a] = fmaf(wr[a][i], hv.x, sre[a]);
        sre[a] = fmaf(-wim_[a][i], hv.y, sre[a]);
        sim[a] = fmaf(wr[a][i], hv.y, sim[a]);
        sim[a] = fmaf(wim_[a][i], hv.x, sim[a]);
      }
    }
#pragma unroll
    for (int a = 0; a < 4; ++a)
      part[(jg * 4 + a) * 10 + p8] = make_float2(sre[a], sim[a]);
    __syncthreads();
    if (tid < HH) {
      const int j = tid;
      const float4 q0 = *(const float4*)&part[j * 10];
      const float4 q1 = *(const float4*)&part[j * 10 + 2];
      const float4 q2 = *(const float4*)&part[j * 10 + 4];
      const float4 q3 = *(const float4*)&part[j * 10 + 6];
      const float R = ((q0.x + q0.z) + (q1.x + q1.z)) + ((q2.x + q2.z) + (q3.x + q3.z));
      const float I = ((q0.y + q0.w) + (q1.y + q1.w)) + ((q2.y + q2.w) + (q3.y + q3.w));
      const float hr = bf_re(u) - I;
      const float hi = bf_im(u) + R;
      hbuf[(j & 15) * 8 + (j >> 4)] = make_float2(hr, hi);
      if (s >= WARM) xpl[s * 128 + j] = pack_bf(hr, hi);
    }
    __syncthreads();
  }

  const int og = tid & 15;
  const int tg2 = tid >> 4;
  float orr[4][4];
#pragma unroll
  for (int a = 0; a < 4; ++a)
#pragma unroll
    for (int t = 0; t < 4; ++t) orr[a][t] = 0.f;
#pragma unroll 1
  for (int kp = 0; kp < 2; ++kp) {
    __syncthreads();
    for (int idx = tid; idx < DOUT * 64; idx += 256) {
      const int o = idx >> 6, hh = idx & 63;
      woA[hh * 64 + o] = pack_bf(wor[(size_t)o * HH + kp * 64 + hh],
                                 woi[(size_t)o * HH + kp * 64 + hh]);
    }
    __syncthreads();
    for (int hh = 0; hh < 64; ++hh) {
      const uint4 wv = *(const uint4*)&woA[hh * 64 + og * 4];
      float wre[4], wimv[4];
      wre[0] = bf_re(wv.x); wimv[0] = bf_im(wv.x);
      wre[1] = bf_re(wv.y); wimv[1] = bf_im(wv.y);
      wre[2] = bf_re(wv.z); wimv[2] = bf_im(wv.z);
      wre[3] = bf_re(wv.w); wimv[3] = bf_im(wv.w);
#pragma unroll
      for (int tt = 0; tt < 4; ++tt) {
        const uint32_t hu = xpl[(WARM + tg2 * 4 + tt) * 128 + kp * 64 + hh];
        const float hre = bf_re(hu), him = bf_im(hu);
#pragma unroll
        for (int a = 0; a < 4; ++a) {
          orr[a][tt] = fmaf(wre[a], hre, orr[a][tt]);
          orr[a][tt] = fmaf(-wimv[a], him, orr[a][tt]);
        }
      }
    }
  }
#pragma unroll
  for (int tt = 0; tt < 4; ++tt) {
    float* po = out + ((size_t)b * TT + (size_t)c * LCH + tg2 * 4 + tt) * DOUT + og * 4;
    *(float4*)po = make_float4(orr[0][tt], orr[1][tt], orr[2][tt], orr[3][tt]);
  }
}

// ---------------------------------------------------------------------------
extern "C" void kernel_launch(void* const* d_in, const int* in_sizes, int n_in,
                              void* d_out, int out_size, void* d_ws, size_t ws_size,
                              hipStream_t stream) {
  const float* xr  = (const float*)d_in[0];
  const float* xi  = (const float*)d_in[1];
  const float* wir = (const float*)d_in[2];
  const float* wii = (const float*)d_in[3];
  const float* whr = (const float*)d_in[4];
  const float* whi = (const float*)d_in[5];
  const float* wor = (const float*)d_in[6];
  const float* woi = (const float*)d_in[7];
  float* out = (float*)d_out;
  (void)in_sizes; (void)n_in; (void)out_size;

  const size_t NEED = 3145728;   // 3 MB (same layout as R9; counter in P slot 0)
  if (ws_size >= NEED) {
    float2* Wp0 = (float2*)d_ws;
    float2* Wp1 = Wp0 + 16384;
    float2* Wp2 = Wp1 + 16384;
    float2* Wp3 = Wp2 + 16384;
    float2* P   = Wp3 + 16384;                       // slots 0..31 (slot 0 unused)
    short*  Wfr = (short*)(P + (size_t)32 * 8192);
    uint32_t* cnt = (uint32_t*)P;                    // barrier counter in slot 0

    hipMemsetAsync(cnt, 0, 16, stream);              // zero the counter
    k_mega<<<256, 512, 0, stream>>>(xr, xi, wir, wii, whr, whi, wor, woi,
                                    out, Wp0, Wp1, Wp2, Wp3, P, Wfr, cnt);
  } else {
    k_fused<<<(TT / LCH) * BB, 256, 0, stream>>>(
        xr, xi, wir, wii, whr, whi, wor, woi, out);
  }
}